// Round 2
// baseline (1712.290 us; speedup 1.0000x reference)
//
#include <hip/hip_runtime.h>
#include <hip/hip_bf16.h>

typedef __hip_bfloat16 bf16;
typedef __attribute__((ext_vector_type(8))) short short8;
typedef __attribute__((ext_vector_type(4))) float f32x4;

static __device__ __forceinline__ float b2f(bf16 x){ return __bfloat162float(x); }
static __device__ __forceinline__ bf16  f2b(float x){ return __float2bfloat16(x); }
static __device__ __forceinline__ short f2bs(float x){ bf16 h = f2b(x); short s; __builtin_memcpy(&s, &h, 2); return s; }

// ---------------- problem dims ----------------
// B=8 L=128 H=512 V=10000 NL=8 NH=8 hd=64 FF=2048, BL=1024

// ---------------- workspace layout ----------------
constexpr size_t AL2(size_t x){ return (x + 255) & ~(size_t)255; }
constexpr size_t SCAL_OFF  = 0;                                    // 256 floats: [0]=s0 [1]=s1 [2]=dmax [4..132)=rel_w
constexpr size_t BIASF_OFF = AL2(SCAL_OFF + 256*4);                // 50176 floats of fp32 biases
constexpr size_t MASK_OFF  = AL2(BIASF_OFF + 50176*4);
constexpr size_t HEIGHT_OFF= AL2(MASK_OFF + 1024*4);
constexpr size_t DIST_OFF  = AL2(HEIGHT_OFF + 1024*4);
constexpr size_t E_OFF     = AL2(DIST_OFF + 1024*4);
constexpr size_t P_OFF     = AL2(E_OFF + 1024*4);                  // [8][132]
constexpr size_t H0_OFF    = AL2(P_OFF + 8*132*4);                 // fp32 residual stream
constexpr size_t TMPF_OFF  = AL2(H0_OFF + (size_t)1024*512*4);
constexpr size_t HMBF_OFF  = AL2(TMPF_OFF + (size_t)1024*512*4);
constexpr size_t HBF_OFF   = AL2(HMBF_OFF + (size_t)1024*512*2);
constexpr size_t ZBF_OFF   = AL2(HBF_OFF + (size_t)1024*512*2);
constexpr size_t QKV_OFF   = AL2(ZBF_OFF + (size_t)1024*512*2);    // [1024][1536]; reused late as embB
constexpr size_t VT_OFF    = AL2(QKV_OFF + (size_t)1024*1536*2);   // [64][64][128]
constexpr size_t WATT_OFF  = AL2(VT_OFF + (size_t)64*64*128*2);    // [64][128][128]
constexpr size_t OBF_OFF   = AL2(WATT_OFF + (size_t)64*128*128*2);
constexpr size_t FF1_OFF   = AL2(OBF_OFF + (size_t)1024*512*2);    // [1024][2048]
constexpr size_t ACOL_OFF  = AL2(FF1_OFF + (size_t)1024*2048*2);   // im2col [1024][4608]
constexpr size_t BML_OFF   = AL2(ACOL_OFF + (size_t)1024*4608*2);
constexpr size_t BMR_OFF   = AL2(BML_OFF + (size_t)8*128*128*4);
constexpr size_t HEADP_OFF = AL2(BMR_OFF + (size_t)8*128*128*4);
constexpr size_t PWT_OFF   = AL2(HEADP_OFF + (size_t)8*128*128*4); // transposed bf16 weights
constexpr size_t DWT_OFF   = AL2(PWT_OFF + (size_t)4*4608*512*2);
constexpr size_t HW1T_OFF  = AL2(DWT_OFF + (size_t)1024*512*2);
constexpr size_t QKVT_OFF  = AL2(HW1T_OFF + (size_t)512*512*2);    // [8][1536][512]
constexpr size_t OWT_OFF   = AL2(QKVT_OFF + (size_t)8*1536*512*2);
constexpr size_t F1T_OFF   = AL2(OWT_OFF + (size_t)8*512*512*2);   // [8][2048][512]
constexpr size_t F2T_OFF   = AL2(F1T_OFF + (size_t)8*2048*512*2);  // [8][512][2048]
constexpr size_t WS_NEED   = AL2(F2T_OFF + (size_t)8*512*2048*2);
// embB (10000x512 bf16 = 10.24 MB) overlaps QKV..FF1 scratch (11.5 MB), used only after the transformer loop.

// ---------------- bias prep + scalars (all inputs fp32) ----------------
// biasf segments (float idx): pcb 0..2048, dcb 2048..2560, hb1 2560..3072,
// qkvb 3072..15360, ob 15360..19456, fb1 19456..35840, fb2 35840..39936, outb 39936..49936
__global__ __launch_bounds__(256) void prep_k(
    const float* pcb, const float* dcb, const float* hb1,
    const float* qb, const float* kb, const float* vb, const float* ob,
    const float* fb1, const float* fb2, const float* outb,
    const float* relraw, const float* sraw,
    float* biasf, float* scal)
{
  int i = blockIdx.x*256 + threadIdx.x;
  if      (i < 2048)  biasf[i] = pcb[i];
  else if (i < 2560)  biasf[i] = dcb[i-2048];
  else if (i < 3072)  biasf[i] = hb1[i-2560];
  else if (i < 15360){ int j = i-3072; int l = j/1536, n = j%1536;
    biasf[i] = (n<512 ? qb[l*512+n] : n<1024 ? kb[l*512+n-512] : vb[l*512+n-1024]); }
  else if (i < 19456) biasf[i] = ob[i-15360];
  else if (i < 35840) biasf[i] = fb1[i-19456];
  else if (i < 39936) biasf[i] = fb2[i-35840];
  else if (i < 49936) biasf[i] = outb[i-39936];
  else if (i == 49936) scal[0] = expf(sraw[0]);
  else if (i == 49937) scal[1] = expf(sraw[1]);
  else if (i == 49938) scal[2] = 0.f;   // dmax accumulator
  else if (i < 49939 + 128){ int q = i - 49939; int p = q>>1;
    float e0 = expf(relraw[2*p]), e1 = expf(relraw[2*p+1]);
    float r0 = e0/(e0+e1);
    scal[4 + q] = (q&1) ? (1.f - r0) : r0; }
}

// ---------------- fused all-weights transpose + f32->bf16 cast ----------------
struct TP {
  const float *pw, *dw, *hw1, *qw, *kw, *vw, *ow, *f1, *f2;
  bf16 *pwT, *dwT, *hw1T, *qkvT, *owT, *f1T, *f2T;
};
__global__ __launch_bounds__(256) void transpose_all_k(TP tp){
  __shared__ short tl[32*33];
  int blk = blockIdx.x, t = threadIdx.x;
  const float* src; bf16* dst; int R, C, tile;
  if      (blk < 9216){ int l = blk/2304; tile = blk%2304; src = tp.pw + (size_t)l*2359296; dst = tp.pwT + (size_t)l*2359296; R=4608; C=512; }
  else if (blk < 9728){ tile = blk-9216; src = tp.dw;  dst = tp.dwT;  R=1024; C=512; }
  else if (blk < 9984){ tile = blk-9728; src = tp.hw1; dst = tp.hw1T; R=512;  C=512; }
  else if (blk < 12032){ int j=blk-9984;  int l=j>>8; tile=j&255;  src = tp.qw + (size_t)l*262144; dst = tp.qkvT + (size_t)l*786432;           R=512; C=512; }
  else if (blk < 14080){ int j=blk-12032; int l=j>>8; tile=j&255;  src = tp.kw + (size_t)l*262144; dst = tp.qkvT + (size_t)l*786432 + 262144;  R=512; C=512; }
  else if (blk < 16128){ int j=blk-14080; int l=j>>8; tile=j&255;  src = tp.vw + (size_t)l*262144; dst = tp.qkvT + (size_t)l*786432 + 524288;  R=512; C=512; }
  else if (blk < 18176){ int j=blk-16128; int l=j>>8; tile=j&255;  src = tp.ow + (size_t)l*262144; dst = tp.owT + (size_t)l*262144;            R=512; C=512; }
  else if (blk < 26368){ int j=blk-18176; int l=j>>10; tile=j&1023; src = tp.f1 + (size_t)l*1048576; dst = tp.f1T + (size_t)l*1048576;         R=512; C=2048; }
  else                 { int j=blk-26368; int l=j>>10; tile=j&1023; src = tp.f2 + (size_t)l*1048576; dst = tp.f2T + (size_t)l*1048576;         R=2048; C=512; }
  int tc = C >> 5;
  int r0 = (tile/tc)*32, c0 = (tile%tc)*32;
  int tx = t & 31, ty = t >> 5;
  short* d = (short*)dst;
  #pragma unroll
  for (int p=0;p<4;p++){ int r = ty + p*8; tl[r*33+tx] = f2bs(src[(size_t)(r0+r)*C + c0 + tx]); }
  __syncthreads();
  #pragma unroll
  for (int p=0;p<4;p++){ int cc = ty + p*8; d[(size_t)(c0+cc)*R + r0 + tx] = tl[tx*33+cc]; }
}

// ---------------- embedding gather (fp32 emb) + mask ----------------
__global__ __launch_bounds__(256) void embed_k(const int* x, const float* emb, float* h0, bf16* hm, int* mask){
  int m = blockIdx.x, t = threadIdx.x;
  int xi = x[m]; int mk = (xi != 0) ? 1 : 0;
  if (t == 0) mask[m] = mk;
  const float* e = emb + (size_t)xi*512;
  float e0 = e[t], e1 = e[t+256];
  h0[(size_t)m*512+t]     = e0;
  h0[(size_t)m*512+t+256] = e1;
  bf16 z = f2b(0.f);
  hm[(size_t)m*512+t]     = mk ? f2b(e0) : z;
  hm[(size_t)m*512+t+256] = mk ? f2b(e1) : z;
}

// ---------------- emb -> bf16 cast for tied output projection ----------------
__global__ __launch_bounds__(256) void embcast_k(const float* e, bf16* o){
  size_t i = (size_t)blockIdx.x*1024 + threadIdx.x*4;
  float4 v = *(const float4*)(e + i);
  o[i]   = f2b(v.x); o[i+1] = f2b(v.y);
  o[i+2] = f2b(v.z); o[i+3] = f2b(v.w);
}

// ---------------- im2col ----------------
__global__ __launch_bounds__(64) void im2col9_k(const bf16* hsrc, bf16* acol){
  int m = blockIdx.x, k = blockIdx.y, t = threadIdx.x;
  int tt = m & 127; int st = tt + k - 4;
  int4* dst = (int4*)(acol + (size_t)m*4608 + (size_t)k*512);
  if (st >= 0 && st < 128){ const int4* s = (const int4*)(hsrc + (size_t)(m + k - 4)*512); dst[t] = s[t]; }
  else dst[t] = make_int4(0,0,0,0);
}
__global__ __launch_bounds__(64) void im2col2_k(const bf16* hsrc, bf16* acol){
  int m = blockIdx.x, k = blockIdx.y, t = threadIdx.x;
  int tt = m & 127; int st = tt + k;
  int4* dst = (int4*)(acol + (size_t)m*1024 + (size_t)k*512);
  if (st < 128){ const int4* s = (const int4*)(hsrc + (size_t)(m + k)*512); dst[t] = s[t]; }
  else dst[t] = make_int4(0,0,0,0);
}

// ---------------- layernorm kernels (H=512, 256 threads) ----------------
__device__ __forceinline__ float blkSum256(float v, float* red){
  #pragma unroll
  for (int o=32;o>0;o>>=1) v += __shfl_down(v, o);
  __syncthreads();
  if ((threadIdx.x & 63) == 0) red[threadIdx.x >> 6] = v;
  __syncthreads();
  return red[0]+red[1]+red[2]+red[3];
}
__global__ __launch_bounds__(256) void ln_tanh_k(const float* X, bf16* outm, bf16* outp, const int* mask){
  __shared__ float red[4];
  int row = blockIdx.x, t = threadIdx.x;
  const float* x = X + (size_t)row*512;
  float a0 = x[t], a1 = x[t+256];
  float mean = blkSum256(a0+a1, red)*(1.f/512.f);
  float d0 = a0-mean, d1 = a1-mean;
  float var = blkSum256(d0*d0+d1*d1, red)*(1.f/512.f);
  float inv = rsqrtf(var + 1e-5f);
  float y0 = tanhf(d0*inv), y1 = tanhf(d1*inv);
  int mk = mask[row];
  size_t o = (size_t)row*512 + t;
  outp[o] = f2b(y0); outp[o+256] = f2b(y1);
  outm[o] = mk ? f2b(y0) : f2b(0.f);
  outm[o+256] = mk ? f2b(y1) : f2b(0.f);
}
__global__ __launch_bounds__(256) void ln_affine_k(const float* X, const float* g, const float* bb, bf16* out){
  __shared__ float red[4];
  int row = blockIdx.x, t = threadIdx.x;
  const float* x = X + (size_t)row*512;
  float a0 = x[t], a1 = x[t+256];
  float mean = blkSum256(a0+a1, red)*(1.f/512.f);
  float d0 = a0-mean, d1 = a1-mean;
  float var = blkSum256(d0*d0+d1*d1, red)*(1.f/512.f);
  float inv = rsqrtf(var + 1e-5f);
  size_t o = (size_t)row*512 + t;
  out[o]     = f2b(d0*inv*g[t]     + bb[t]);
  out[o+256] = f2b(d1*inv*g[t+256] + bb[t+256]);
}

// ---------------- row-dot heads (height / distance), fp32 weights ----------------
__global__ __launch_bounds__(256) void rowdot_k(const bf16* X, const float* w, const float* bsc,
                                                const int* mask, float* out, int mode){
  int wv = threadIdx.x>>6, lane = threadIdx.x&63;
  int m = blockIdx.x*4 + wv;
  const bf16* x = X + (size_t)m*512;
  float s = 0.f;
  #pragma unroll
  for (int i=0;i<8;++i){ int c = i*64 + lane; s += b2f(x[c])*w[c]; }
  #pragma unroll
  for (int o=32;o>0;o>>=1) s += __shfl_down(s,o);
  if (lane==0){
    float v = s + bsc[0];
    if (mode==0) out[m] = (mask[m]!=0) ? v : -1e9f;
    else { int tt = m & 127; bool ms = (tt<127) && (mask[m+1]!=0); out[m] = ms ? v : 1e9f; }
  }
}

// ---------------- margin normalization: global max ----------------
__global__ __launch_bounds__(128) void margin_k(const float* height, const float* dist, const int* mask, float* scal){
  int b = blockIdx.x, i = threadIdx.x;
  __shared__ float hg[128], ds[128], red[128];
  hg[i] = height[b*128+i]; ds[i] = dist[b*128+i];
  __syncthreads();
  float dpi = (i==0) ? 1e9f : ds[i-1];
  float hmr = -3.0e38f, best = 0.f;
  for (int j=i; j<128; ++j){
    hmr = fmaxf(hmr, hg[j]);
    float mg = fminf(fmaxf(dpi - hmr, 0.f), fmaxf(ds[j] - hmr, 0.f));
    bool mm = (i==0) ? ((j<127) && (mask[b*128+j+1]!=0)) : (mask[b*128+j]!=0);
    if (mm) best = fmaxf(best, mg);
  }
  red[i] = best; __syncthreads();
  for (int s=64; s>0; s>>=1){ if (i<s) red[i] = fmaxf(red[i], red[i+s]); __syncthreads(); }
  if (i==0) atomicMax((unsigned int*)(scal+2), __float_as_uint(red[0]));
}

// ---------------- e = exp(s1*(height-hmax)), prefix sums ----------------
__global__ __launch_bounds__(128) void ep_k(const float* height, const float* scal, float* e, float* P){
  int b = blockIdx.x, l = threadIdx.x;
  __shared__ float red[128], sc[128];
  float h = height[b*128+l];
  red[l] = h; __syncthreads();
  for (int s=64;s>0;s>>=1){ if (l<s) red[l] = fmaxf(red[l], red[l+s]); __syncthreads(); }
  float hmax = red[0];
  float ev = expf(scal[1]*(h - hmax));
  e[b*128+l] = ev;
  sc[l] = ev; __syncthreads();
  for (int off=1; off<128; off<<=1){
    float a = (l>=off) ? sc[l-off] : 0.f;
    __syncthreads(); sc[l] += a; __syncthreads();
  }
  P[b*132 + l + 1] = sc[l];
  if (l==0) P[b*132] = 0.f;
}

// ---------------- gamma -> bml/bmr via sequential cummin scans ----------------
__global__ __launch_bounds__(128) void gbml_k(const float* height, const float* dist, const float* scal,
                                              float* bml, float* bmr){
  int b = blockIdx.x, l = threadIdx.x;
  __shared__ float dAdj[128], hg[128];
  float dmax = scal[2], s0 = scal[0];
  dAdj[l] = dist[b*128+l] - dmax; hg[l] = height[b*128+l];
  __syncthreads();
  float hl = hg[l];
  float* BML = bml + ((size_t)b*128 + l)*128;
  float* BMR = bmr + ((size_t)b*128 + l)*128;
  for (int j=l+1; j<128; ++j) BML[j] = 0.f;
  float cmn = 1.f;
  for (int j=l-1; j>=0; --j){
    float g = 1.f/(1.f + expf(-(hl - dAdj[j])*s0));
    float cmj = fminf(g, cmn);
    BML[j+1] = cmn - cmj;
    cmn = cmj;
  }
  BML[0] = cmn;
  for (int j=0; j<l; ++j) BMR[j] = 0.f;
  float cmp_ = 1.f;
  for (int j=l+1; j<128; ++j){
    float g = 1.f/(1.f + expf(-(hl - dAdj[j-1])*s0));
    float cmj = fminf(g, cmp_);
    BMR[j-1] = cmp_ - cmj;
    cmp_ = cmj;
  }
  BMR[127] = cmp_;
}

// ---------------- head via separable prefix/suffix sums ----------------
__global__ __launch_bounds__(128) void head_k(const float* bml, const float* bmr, const float* e,
                                              const float* P, float* head){
  int bl = blockIdx.x; int b = bl>>7, l = bl&127; int h = threadIdx.x;
  __shared__ float bmlS[128], bmrS[128], eS[128], PS[129], U[128], Vv[128];
  bmlS[h] = bml[(size_t)bl*128 + h];
  bmrS[h] = bmr[(size_t)bl*128 + h];
  eS[h]   = e[b*128+h];
  PS[h]   = P[b*132+h];
  if (h==0) PS[128] = P[b*132+128];
  __syncthreads();
  float u = 0.f, v = 0.f;
  if (h <= l){
    float bh = bmlS[h];
    if (bh > 0.f){
      float ph = PS[h]; float acc = 0.f;
      for (int j=l; j<128; ++j){
        float br = bmrS[j]; float den = PS[j+1] - ph;
        if (br > 0.f && den > 1e-30f) acc += br/den;
      }
      u = bh*acc;
    }
  } else {
    float br = bmrS[h];
    if (br > 0.f){
      float p1 = PS[h+1]; float acc = 0.f;
      for (int i=0;i<=l;++i){
        float bm = bmlS[i]; float den = p1 - PS[i];
        if (bm > 0.f && den > 1e-30f) acc += bm/den;
      }
      v = br*acc;
    }
  }
  U[h] = u; Vv[h] = v; __syncthreads();
  for (int off=1; off<128; off<<=1){
    float a  = (h>=off)      ? U[h-off]  : 0.f;
    float bs = (h+off<128)   ? Vv[h+off] : 0.f;
    __syncthreads();
    U[h] += a; Vv[h] += bs;
    __syncthreads();
  }
  float a = (h<l) ? U[h] : (h>l) ? Vv[h] : 0.f;   // eye zeroed at h==l
  head[(size_t)bl*128 + h] = eS[h]*a;
}

// ---------------- v -> vT per (b,head) ----------------
__global__ __launch_bounds__(256) void vtrans_k(const bf16* qkv, bf16* vt){
  __shared__ short tl[64*130];
  const short* q = (const short*)qkv; short* v = (short*)vt;
  int z = blockIdx.x, t = threadIdx.x; int b = z>>3, h = z&7;
  for (int i=t; i<8192; i+=256){ int l = i>>6, d = i&63;
    tl[d*130 + l] = q[((size_t)(b*128+l))*1536 + 1024 + h*64 + d]; }
  __syncthreads();
  for (int i=t; i<8192; i+=256){ v[(size_t)z*8192 + i] = tl[(i>>7)*130 + (i&127)]; }
}

// ---------------- MFMA NT GEMM: C[M,N] = A[M,K] @ Bt[N,K]^T (+epilogues) ----------------
enum GMode { GM_F32=0, GM_BF16=1, GM_LEAKY=2, GM_ADD=3, GM_SIGDEP=4 };

template<int MODE>
__global__ __launch_bounds__(256) void gemm_nt(
    const bf16* __restrict__ Ab, int lda, long long sA1, long long sA2,
    const bf16* __restrict__ Bb, int ldb, long long sB1, long long sB2,
    void* __restrict__ Cb, int ldc, long long sC1, long long sC2,
    int M, int N, int K,
    const float* __restrict__ bias,
    const int* __restrict__ maskp, const float* __restrict__ headp,
    const float* __restrict__ scal, int layer)
{
  __shared__ short As[64*72];
  __shared__ short Bs[64*72];
  const int t = threadIdx.x;
  const int z = blockIdx.z, zb = z>>3, zh = z&7;
  const bf16* A  = Ab + (size_t)zb*sA1 + (size_t)zh*sA2 + (size_t)blockIdx.y*64*lda;
  const bf16* Bp = Bb + (size_t)zb*sB1 + (size_t)zh*sB2;
  const int n0 = blockIdx.x*64;
  const int wv = t>>6, ln = t&63;
  const int wm = wv>>1, wn = wv&1;          // 2x2 wave layout, each wave 32x32
  const int r0 = t>>3, cc0 = (t&7)*8;       // staging coords
  f32x4 acc[2][2];
  #pragma unroll
  for (int mi=0;mi<2;++mi)
    #pragma unroll
    for (int ci=0;ci<2;++ci) acc[mi][ci] = (f32x4){0.f,0.f,0.f,0.f};

  for (int k0=0; k0<K; k0+=64){
    #pragma unroll
    for (int p=0;p<2;++p){
      int r = r0 + p*32;
      *(int4*)(&As[r*72+cc0]) = *(const int4*)(A + (size_t)r*lda + k0 + cc0);
      int gn = n0 + r;
      int4 vb = make_int4(0,0,0,0);
      if (gn < N) vb = *(const int4*)(Bp + (size_t)gn*ldb + k0 + cc0);
      *(int4*)(&Bs[r*72+cc0]) = vb;
    }
    __syncthreads();
    #pragma unroll
    for (int kk=0; kk<64; kk+=32){
      short8 av[2], bv[2];
      #pragma unroll
      for (int mi=0;mi<2;++mi)
        av[mi] = *(const short8*)(&As[(wm*32 + mi*16 + (ln&15))*72 + kk + (ln>>4)*8]);
      #pragma unroll
      for (int ci=0;ci<2;++ci)
        bv[ci] = *(const short8*)(&Bs[(wn*32 + ci*16 + (ln&15))*72 + kk + (ln>>4)*8]);
      #pragma unroll
      for (int mi=0;mi<2;++mi)
        #pragma unroll
        for (int ci=0;ci<2;++ci)
          acc[mi][ci] = __builtin_amdgcn_mfma_f32_16x16x32_bf16(av[mi], bv[ci], acc[mi][ci], 0,0,0);
    }
    __syncthreads();
  }
  const int cin = ln & 15;
  #pragma unroll
  for (int mi=0;mi<2;++mi){
    #pragma unroll
    for (int ci=0;ci<2;++ci){
      int col = n0 + wn*32 + ci*16 + cin;
      if (col >= N) continue;
      #pragma unroll
      for (int r=0;r<4;++r){
        int row = blockIdx.y*64 + wm*32 + mi*16 + ((ln>>4)<<2) + r;
        float v = acc[mi][ci][r];
        size_t coff = (size_t)zb*sC1 + (size_t)zh*sC2 + (size_t)row*ldc + col;
        if (MODE == GM_F32){
          if (bias) v += bias[col];
          ((float*)Cb)[coff] = v;
        } else if (MODE == GM_BF16){
          if (bias) v += bias[col];
          ((bf16*)Cb)[coff] = f2b(v);
        } else if (MODE == GM_LEAKY){
          v += bias[col];
          v = (v > 0.f) ? v : 0.01f*v;
          ((bf16*)Cb)[coff] = f2b(v);
        } else if (MODE == GM_ADD){
          float* p = ((float*)Cb) + coff;
          *p += v + bias[col];
        } else { // GM_SIGDEP: w = sigmoid(qk/8 + kpm) * (rw0*head[l,m] + rw1*head[m,l])
          float outv = 0.f;
          if (maskp[zb*128 + col] != 0){
            float sg = 1.f/(1.f + expf(-v*0.125f));
            float h1 = headp[((size_t)zb*128 + row)*128 + col];
            float h2 = headp[((size_t)zb*128 + col)*128 + row];
            float rw0 = scal[4 + (layer*8 + zh)*2];
            float rw1 = scal[4 + (layer*8 + zh)*2 + 1];
            outv = sg*(rw0*h1 + rw1*h2);
          }
          ((bf16*)Cb)[coff] = f2b(outv);
        }
      }
    }
  }
}

// ---------------- launch ----------------
extern "C" void kernel_launch(void* const* d_in, const int* in_sizes, int n_in,
                              void* d_out, int out_size, void* d_ws, size_t ws_size,
                              hipStream_t stream)
{
  if (ws_size < WS_NEED) return;  // need ~97 MB of scratch
  const int*   x    = (const int*)d_in[0];
  const float* emb  = (const float*)d_in[2];
  const float* pw   = (const float*)d_in[3];
  const float* pcb  = (const float*)d_in[4];
  const float* dw   = (const float*)d_in[5];
  const float* dcb  = (const float*)d_in[6];
  const float* dlw  = (const float*)d_in[7];
  const float* dlb  = (const float*)d_in[8];
  const float* hw1  = (const float*)d_in[9];
  const float* hb1  = (const float*)d_in[10];
  const float* hw2  = (const float*)d_in[11];
  const float* hb2  = (const float*)d_in[12];
  const float* relw = (const float*)d_in[13];
  const float* sraw = (const float*)d_in[14];
  const float* alg  = (const float*)d_in[15];
  const float* alb  = (const float*)d_in[16];
  const float* qw   = (const float*)d_in[17];
  const float* qb   = (const float*)d_in[18];
  const float* kw   = (const float*)d_in[19];
  const float* kb   = (const float*)d_in[20];
  const float* vw   = (const float*)d_in[21];
  const float* vb   = (const float*)d_in[22];
  const float* ow   = (const float*)d_in[23];
  const float* ob   = (const float*)d_in[24];
  const float* flg  = (const float*)d_in[25];
  const float* flb  = (const float*)d_in[26];
  const float* f1   = (const float*)d_in[27];
  const float* fb1  = (const float*)d_in[28];
  const float* f2   = (const float*)d_in[29];
  const float* fb2  = (const float*)d_in[30];
  const float* fng  = (const float*)d_in[31];
  const float* fnb  = (const float*)d_in[32];
  const float* outb = (const float*)d_in[33];

  char* ws = (char*)d_ws;
  float* scal    = (float*)(ws + SCAL_OFF);
  float* biasf   = (float*)(ws + BIASF_OFF);
  int*   maskp   = (int*)(ws + MASK_OFF);
  float* heightp = (float*)(ws + HEIGHT_OFF);
  float* distp   = (float*)(ws + DIST_OFF);
  float* e_p     = (float*)(ws + E_OFF);
  float* P_p     = (float*)(ws + P_OFF);
  float* h0      = (float*)(ws + H0_OFF);
  float* tmpf    = (float*)(ws + TMPF_OFF);
  bf16* hm_bf    = (bf16*)(ws + HMBF_OFF);
  bf16* h_bf     = (bf16*)(ws + HBF_OFF);
  bf16* z_bf     = (bf16*)(ws + ZBF_OFF);
  bf16* qkvp     = (bf16*)(ws + QKV_OFF);
  bf16* vtp      = (bf16*)(ws + VT_OFF);
  bf16* wattp    = (bf16*)(ws + WATT_OFF);
  bf16* o_bf     = (bf16*)(ws + OBF_OFF);
  bf16* ff1p     = (bf16*)(ws + FF1_OFF);
  bf16* acol     = (bf16*)(ws + ACOL_OFF);
  float* bmlp    = (float*)(ws + BML_OFF);
  float* bmrp    = (float*)(ws + BMR_OFF);
  float* headp   = (float*)(ws + HEADP_OFF);
  bf16* pwT      = (bf16*)(ws + PWT_OFF);
  bf16* dwT      = (bf16*)(ws + DWT_OFF);
  bf16* hw1T     = (bf16*)(ws + HW1T_OFF);
  bf16* qkvT     = (bf16*)(ws + QKVT_OFF);
  bf16* owT      = (bf16*)(ws + OWT_OFF);
  bf16* f1T      = (bf16*)(ws + F1T_OFF);
  bf16* f2T      = (bf16*)(ws + F2T_OFF);
  bf16* embB     = (bf16*)(ws + QKV_OFF);   // reuse attention scratch after the loop

  prep_k<<<196,256,0,stream>>>(pcb,dcb,hb1,qb,kb,vb,ob,fb1,fb2,outb,relw,sraw,biasf,scal);
  TP tp{pw,dw,hw1,qw,kw,vw,ow,f1,f2, pwT,dwT,hw1T,qkvT,owT,f1T,f2T};
  transpose_all_k<<<34560,256,0,stream>>>(tp);
  embed_k<<<1024,256,0,stream>>>(x, emb, h0, hm_bf, maskp);

  // parser: 4x (conv K=9 -> LN -> tanh)
  for (int i=0;i<4;++i){
    im2col9_k<<<dim3(1024,9),64,0,stream>>>(hm_bf, acol);
    gemm_nt<GM_F32><<<dim3(8,16,1),256,0,stream>>>(acol,4608,0,0, pwT+(size_t)i*2359296,4608,0,0,
        tmpf,512,0,0, 1024,512,4608, biasf + i*512, nullptr,nullptr,nullptr,0);
    ln_tanh_k<<<1024,256,0,stream>>>(tmpf, hm_bf, h_bf, maskp);
  }
  // height head
  gemm_nt<GM_F32><<<dim3(8,16,1),256,0,stream>>>(h_bf,512,0,0, hw1T,512,0,0,
      tmpf,512,0,0, 1024,512,512, biasf + 2560, nullptr,nullptr,nullptr,0);
  ln_tanh_k<<<1024,256,0,stream>>>(tmpf, hm_bf, z_bf, maskp);
  rowdot_k<<<256,256,0,stream>>>(z_bf, hw2, hb2, maskp, heightp, 0);
  ep_k<<<8,128,0,stream>>>(heightp, scal, e_p, P_p);
  // distance head (conv K=2, shift)
  im2col2_k<<<dim3(1024,2),64,0,stream>>>(h_bf, acol);
  gemm_nt<GM_F32><<<dim3(8,16,1),256,0,stream>>>(acol,1024,0,0, dwT,1024,0,0,
      tmpf,512,0,0, 1024,512,1024, biasf + 2048, nullptr,nullptr,nullptr,0);
  ln_tanh_k<<<1024,256,0,stream>>>(tmpf, hm_bf, z_bf, maskp);
  rowdot_k<<<256,256,0,stream>>>(z_bf, dlw, dlb, maskp, distp, 1);
  // margin normalization, block decomposition, head distribution
  margin_k<<<8,128,0,stream>>>(heightp, distp, maskp, scal);
  gbml_k<<<8,128,0,stream>>>(heightp, distp, scal, bmlp, bmrp);
  head_k<<<1024,128,0,stream>>>(bmlp, bmrp, e_p, P_p, headp);

  // transformer
  for (int l=0;l<8;++l){
    ln_affine_k<<<1024,256,0,stream>>>(h0, alg + l*512, alb + l*512, z_bf);
    gemm_nt<GM_BF16><<<dim3(24,16,1),256,0,stream>>>(z_bf,512,0,0, qkvT+(size_t)l*786432,512,0,0,
        qkvp,1536,0,0, 1024,1536,512, biasf + 3072 + l*1536, nullptr,nullptr,nullptr,0);
    vtrans_k<<<64,256,0,stream>>>(qkvp, vtp);
    gemm_nt<GM_SIGDEP><<<dim3(2,2,64),256,0,stream>>>(qkvp,1536,196608,64, qkvp+512,1536,196608,64,
        wattp,128,131072,16384, 128,128,64, nullptr, maskp, headp, scal, l);
    gemm_nt<GM_BF16><<<dim3(1,2,64),256,0,stream>>>(wattp,128,131072,16384, vtp,128,65536,8192,
        o_bf,512,65536,64, 128,64,128, nullptr, nullptr,nullptr,nullptr,0);
    gemm_nt<GM_ADD><<<dim3(8,16,1),256,0,stream>>>(o_bf,512,0,0, owT+(size_t)l*262144,512,0,0,
        h0,512,0,0, 1024,512,512, biasf + 15360 + l*512, nullptr,nullptr,nullptr,0);
    ln_affine_k<<<1024,256,0,stream>>>(h0, flg + l*512, flb + l*512, z_bf);
    gemm_nt<GM_LEAKY><<<dim3(32,16,1),256,0,stream>>>(z_bf,512,0,0, f1T+(size_t)l*1048576,512,0,0,
        ff1p,2048,0,0, 1024,2048,512, biasf + 19456 + l*2048, nullptr,nullptr,nullptr,0);
    gemm_nt<GM_ADD><<<dim3(8,16,1),256,0,stream>>>(ff1p,2048,0,0, f2T+(size_t)l*1048576,2048,0,0,
        h0,512,0,0, 1024,512,2048, biasf + 35840 + l*512, nullptr,nullptr,nullptr,0);
  }
  // final LN + tied-embedding projection (fp32 out)
  ln_affine_k<<<1024,256,0,stream>>>(h0, fng, fnb, z_bf);
  embcast_k<<<5000,256,0,stream>>>(emb, embB);
  gemm_nt<GM_F32><<<dim3(157,16,1),256,0,stream>>>(z_bf,512,0,0, embB,512,0,0,
      d_out,10000,0,0, 1024,10000,512, biasf + 39936, nullptr,nullptr,nullptr,0);
}

// Round 3
// 1085.315 us; speedup vs baseline: 1.5777x; 1.5777x over previous
//
#include <hip/hip_runtime.h>
#include <hip/hip_bf16.h>

typedef __hip_bfloat16 bf16;
typedef __attribute__((ext_vector_type(8))) short short8;
typedef __attribute__((ext_vector_type(4))) float f32x4;

static __device__ __forceinline__ float b2f(bf16 x){ return __bfloat162float(x); }
static __device__ __forceinline__ bf16  f2b(float x){ return __float2bfloat16(x); }
static __device__ __forceinline__ short f2bs(float x){ bf16 h = f2b(x); short s; __builtin_memcpy(&s, &h, 2); return s; }

#define GLOBAL_AS __attribute__((address_space(1)))
#define LDS_AS    __attribute__((address_space(3)))
static __device__ __forceinline__ void gll16(const void* g, short* l){
  __builtin_amdgcn_global_load_lds((const GLOBAL_AS void*)g, (LDS_AS void*)l, 16, 0, 0);
}

// ---------------- problem dims ----------------
// B=8 L=128 H=512 V=10000 NL=8 NH=8 hd=64 FF=2048, BL=1024

// ---------------- workspace layout ----------------
constexpr size_t AL2(size_t x){ return (x + 255) & ~(size_t)255; }
constexpr size_t SCAL_OFF  = 0;                                    // 256 floats: [0]=s0 [1]=s1 [2]=dmax [4..132)=rel_w
constexpr size_t BIASF_OFF = AL2(SCAL_OFF + 256*4);                // 50176 floats of fp32 biases
constexpr size_t MASK_OFF  = AL2(BIASF_OFF + 50176*4);
constexpr size_t HEIGHT_OFF= AL2(MASK_OFF + 1024*4);
constexpr size_t DIST_OFF  = AL2(HEIGHT_OFF + 1024*4);
constexpr size_t E_OFF     = AL2(DIST_OFF + 1024*4);
constexpr size_t P_OFF     = AL2(E_OFF + 1024*4);                  // [8][132]
constexpr size_t H0_OFF    = AL2(P_OFF + 8*132*4);                 // fp32 residual stream
constexpr size_t TMPF_OFF  = AL2(H0_OFF + (size_t)1024*512*4);
constexpr size_t HMBF_OFF  = AL2(TMPF_OFF + (size_t)1024*512*4);
constexpr size_t HBF_OFF   = AL2(HMBF_OFF + (size_t)1024*512*2);
constexpr size_t ZBF_OFF   = AL2(HBF_OFF + (size_t)1024*512*2);
constexpr size_t QKV_OFF   = AL2(ZBF_OFF + (size_t)1024*512*2);    // [1024][1536]; reused late as embB
constexpr size_t VT_OFF    = AL2(QKV_OFF + (size_t)1024*1536*2);   // [64][64][128]
constexpr size_t WATT_OFF  = AL2(VT_OFF + (size_t)64*64*128*2);    // [64][128][128]
constexpr size_t OBF_OFF   = AL2(WATT_OFF + (size_t)64*128*128*2);
constexpr size_t FF1_OFF   = AL2(OBF_OFF + (size_t)1024*512*2);    // [1024][2048]
constexpr size_t ACOL_OFF  = AL2(FF1_OFF + (size_t)1024*2048*2);   // im2col [1024][4608]
constexpr size_t BML_OFF   = AL2(ACOL_OFF + (size_t)1024*4608*2);
constexpr size_t BMR_OFF   = AL2(BML_OFF + (size_t)8*128*128*4);
constexpr size_t HEADP_OFF = AL2(BMR_OFF + (size_t)8*128*128*4);
constexpr size_t PWT_OFF   = AL2(HEADP_OFF + (size_t)8*128*128*4); // transposed bf16 weights
constexpr size_t DWT_OFF   = AL2(PWT_OFF + (size_t)4*4608*512*2);
constexpr size_t HW1T_OFF  = AL2(DWT_OFF + (size_t)1024*512*2);
constexpr size_t QKVT_OFF  = AL2(HW1T_OFF + (size_t)512*512*2);    // [8][1536][512]
constexpr size_t OWT_OFF   = AL2(QKVT_OFF + (size_t)8*1536*512*2);
constexpr size_t F1T_OFF   = AL2(OWT_OFF + (size_t)8*512*512*2);   // [8][2048][512]
constexpr size_t F2T_OFF   = AL2(F1T_OFF + (size_t)8*2048*512*2);  // [8][512][2048]
constexpr size_t WS_NEED   = AL2(F2T_OFF + (size_t)8*512*2048*2);
// embB (10000x512 bf16 = 10.24 MB) overlaps QKV..FF1 scratch (11.5 MB), used only after the transformer loop.

// ---------------- bias prep + scalars (all inputs fp32) ----------------
__global__ __launch_bounds__(256) void prep_k(
    const float* pcb, const float* dcb, const float* hb1,
    const float* qb, const float* kb, const float* vb, const float* ob,
    const float* fb1, const float* fb2, const float* outb,
    const float* relraw, const float* sraw,
    float* biasf, float* scal)
{
  int i = blockIdx.x*256 + threadIdx.x;
  if      (i < 2048)  biasf[i] = pcb[i];
  else if (i < 2560)  biasf[i] = dcb[i-2048];
  else if (i < 3072)  biasf[i] = hb1[i-2560];
  else if (i < 15360){ int j = i-3072; int l = j/1536, n = j%1536;
    biasf[i] = (n<512 ? qb[l*512+n] : n<1024 ? kb[l*512+n-512] : vb[l*512+n-1024]); }
  else if (i < 19456) biasf[i] = ob[i-15360];
  else if (i < 35840) biasf[i] = fb1[i-19456];
  else if (i < 39936) biasf[i] = fb2[i-35840];
  else if (i < 49936) biasf[i] = outb[i-39936];
  else if (i == 49936) scal[0] = expf(sraw[0]);
  else if (i == 49937) scal[1] = expf(sraw[1]);
  else if (i == 49938) scal[2] = 0.f;   // dmax accumulator
  else if (i < 49939 + 128){ int q = i - 49939; int p = q>>1;
    float e0 = expf(relraw[2*p]), e1 = expf(relraw[2*p+1]);
    float r0 = e0/(e0+e1);
    scal[4 + q] = (q&1) ? (1.f - r0) : r0; }
}

// ---------------- fused all-weights transpose + f32->bf16 cast ----------------
struct TP {
  const float *pw, *dw, *hw1, *qw, *kw, *vw, *ow, *f1, *f2;
  bf16 *pwT, *dwT, *hw1T, *qkvT, *owT, *f1T, *f2T;
};
__global__ __launch_bounds__(256) void transpose_all_k(TP tp){
  __shared__ short tl[32*33];
  int blk = blockIdx.x, t = threadIdx.x;
  const float* src; bf16* dst; int R, C, tile;
  if      (blk < 9216){ int l = blk/2304; tile = blk%2304; src = tp.pw + (size_t)l*2359296; dst = tp.pwT + (size_t)l*2359296; R=4608; C=512; }
  else if (blk < 9728){ tile = blk-9216; src = tp.dw;  dst = tp.dwT;  R=1024; C=512; }
  else if (blk < 9984){ tile = blk-9728; src = tp.hw1; dst = tp.hw1T; R=512;  C=512; }
  else if (blk < 12032){ int j=blk-9984;  int l=j>>8; tile=j&255;  src = tp.qw + (size_t)l*262144; dst = tp.qkvT + (size_t)l*786432;           R=512; C=512; }
  else if (blk < 14080){ int j=blk-12032; int l=j>>8; tile=j&255;  src = tp.kw + (size_t)l*262144; dst = tp.qkvT + (size_t)l*786432 + 262144;  R=512; C=512; }
  else if (blk < 16128){ int j=blk-14080; int l=j>>8; tile=j&255;  src = tp.vw + (size_t)l*262144; dst = tp.qkvT + (size_t)l*786432 + 524288;  R=512; C=512; }
  else if (blk < 18176){ int j=blk-16128; int l=j>>8; tile=j&255;  src = tp.ow + (size_t)l*262144; dst = tp.owT + (size_t)l*262144;            R=512; C=512; }
  else if (blk < 26368){ int j=blk-18176; int l=j>>10; tile=j&1023; src = tp.f1 + (size_t)l*1048576; dst = tp.f1T + (size_t)l*1048576;         R=512; C=2048; }
  else                 { int j=blk-26368; int l=j>>10; tile=j&1023; src = tp.f2 + (size_t)l*1048576; dst = tp.f2T + (size_t)l*1048576;         R=2048; C=512; }
  int tc = C >> 5;
  int r0 = (tile/tc)*32, c0 = (tile%tc)*32;
  int tx = t & 31, ty = t >> 5;
  short* d = (short*)dst;
  #pragma unroll
  for (int p=0;p<4;p++){ int r = ty + p*8; tl[r*33+tx] = f2bs(src[(size_t)(r0+r)*C + c0 + tx]); }
  __syncthreads();
  #pragma unroll
  for (int p=0;p<4;p++){ int cc = ty + p*8; d[(size_t)(c0+cc)*R + r0 + tx] = tl[tx*33+cc]; }
}

// ---------------- embedding gather (fp32 emb) + mask ----------------
__global__ __launch_bounds__(256) void embed_k(const int* x, const float* emb, float* h0, bf16* hm, int* mask){
  int m = blockIdx.x, t = threadIdx.x;
  int xi = x[m]; int mk = (xi != 0) ? 1 : 0;
  if (t == 0) mask[m] = mk;
  const float* e = emb + (size_t)xi*512;
  float e0 = e[t], e1 = e[t+256];
  h0[(size_t)m*512+t]     = e0;
  h0[(size_t)m*512+t+256] = e1;
  bf16 z = f2b(0.f);
  hm[(size_t)m*512+t]     = mk ? f2b(e0) : z;
  hm[(size_t)m*512+t+256] = mk ? f2b(e1) : z;
}

// ---------------- emb -> bf16 cast for tied output projection ----------------
__global__ __launch_bounds__(256) void embcast_k(const float* e, bf16* o){
  size_t i = (size_t)blockIdx.x*1024 + threadIdx.x*4;
  float4 v = *(const float4*)(e + i);
  o[i]   = f2b(v.x); o[i+1] = f2b(v.y);
  o[i+2] = f2b(v.z); o[i+3] = f2b(v.w);
}

// ---------------- im2col ----------------
__global__ __launch_bounds__(64) void im2col9_k(const bf16* hsrc, bf16* acol){
  int m = blockIdx.x, k = blockIdx.y, t = threadIdx.x;
  int tt = m & 127; int st = tt + k - 4;
  int4* dst = (int4*)(acol + (size_t)m*4608 + (size_t)k*512);
  if (st >= 0 && st < 128){ const int4* s = (const int4*)(hsrc + (size_t)(m + k - 4)*512); dst[t] = s[t]; }
  else dst[t] = make_int4(0,0,0,0);
}
__global__ __launch_bounds__(64) void im2col2_k(const bf16* hsrc, bf16* acol){
  int m = blockIdx.x, k = blockIdx.y, t = threadIdx.x;
  int tt = m & 127; int st = tt + k;
  int4* dst = (int4*)(acol + (size_t)m*1024 + (size_t)k*512);
  if (st < 128){ const int4* s = (const int4*)(hsrc + (size_t)(m + k)*512); dst[t] = s[t]; }
  else dst[t] = make_int4(0,0,0,0);
}

// ---------------- layernorm kernels (H=512, 256 threads) ----------------
__device__ __forceinline__ float blkSum256(float v, float* red){
  #pragma unroll
  for (int o=32;o>0;o>>=1) v += __shfl_down(v, o);
  __syncthreads();
  if ((threadIdx.x & 63) == 0) red[threadIdx.x >> 6] = v;
  __syncthreads();
  return red[0]+red[1]+red[2]+red[3];
}
// bias added here (split-K GEMMs accumulate raw partials)
__global__ __launch_bounds__(256) void ln_tanh_k(const float* X, const float* bias, bf16* outm, bf16* outp, const int* mask){
  __shared__ float red[4];
  int row = blockIdx.x, t = threadIdx.x;
  const float* x = X + (size_t)row*512;
  float a0 = x[t] + bias[t], a1 = x[t+256] + bias[t+256];
  float mean = blkSum256(a0+a1, red)*(1.f/512.f);
  float d0 = a0-mean, d1 = a1-mean;
  float var = blkSum256(d0*d0+d1*d1, red)*(1.f/512.f);
  float inv = rsqrtf(var + 1e-5f);
  float y0 = tanhf(d0*inv), y1 = tanhf(d1*inv);
  int mk = mask[row];
  size_t o = (size_t)row*512 + t;
  outp[o] = f2b(y0); outp[o+256] = f2b(y1);
  outm[o] = mk ? f2b(y0) : f2b(0.f);
  outm[o+256] = mk ? f2b(y1) : f2b(0.f);
}
__global__ __launch_bounds__(256) void ln_affine_k(const float* X, const float* g, const float* bb, bf16* out){
  __shared__ float red[4];
  int row = blockIdx.x, t = threadIdx.x;
  const float* x = X + (size_t)row*512;
  float a0 = x[t], a1 = x[t+256];
  float mean = blkSum256(a0+a1, red)*(1.f/512.f);
  float d0 = a0-mean, d1 = a1-mean;
  float var = blkSum256(d0*d0+d1*d1, red)*(1.f/512.f);
  float inv = rsqrtf(var + 1e-5f);
  size_t o = (size_t)row*512 + t;
  out[o]     = f2b(d0*inv*g[t]     + bb[t]);
  out[o+256] = f2b(d1*inv*g[t+256] + bb[t+256]);
}

// ---------------- row-dot heads (height / distance), fp32 weights ----------------
__global__ __launch_bounds__(256) void rowdot_k(const bf16* X, const float* w, const float* bsc,
                                                const int* mask, float* out, int mode){
  int wv = threadIdx.x>>6, lane = threadIdx.x&63;
  int m = blockIdx.x*4 + wv;
  const bf16* x = X + (size_t)m*512;
  float s = 0.f;
  #pragma unroll
  for (int i=0;i<8;++i){ int c = i*64 + lane; s += b2f(x[c])*w[c]; }
  #pragma unroll
  for (int o=32;o>0;o>>=1) s += __shfl_down(s,o);
  if (lane==0){
    float v = s + bsc[0];
    if (mode==0) out[m] = (mask[m]!=0) ? v : -1e9f;
    else { int tt = m & 127; bool ms = (tt<127) && (mask[m+1]!=0); out[m] = ms ? v : 1e9f; }
  }
}

// ---------------- margin normalization: global max ----------------
__global__ __launch_bounds__(128) void margin_k(const float* height, const float* dist, const int* mask, float* scal){
  int b = blockIdx.x, i = threadIdx.x;
  __shared__ float hg[128], ds[128], red[128];
  hg[i] = height[b*128+i]; ds[i] = dist[b*128+i];
  __syncthreads();
  float dpi = (i==0) ? 1e9f : ds[i-1];
  float hmr = -3.0e38f, best = 0.f;
  for (int j=i; j<128; ++j){
    hmr = fmaxf(hmr, hg[j]);
    float mg = fminf(fmaxf(dpi - hmr, 0.f), fmaxf(ds[j] - hmr, 0.f));
    bool mm = (i==0) ? ((j<127) && (mask[b*128+j+1]!=0)) : (mask[b*128+j]!=0);
    if (mm) best = fmaxf(best, mg);
  }
  red[i] = best; __syncthreads();
  for (int s=64; s>0; s>>=1){ if (i<s) red[i] = fmaxf(red[i], red[i+s]); __syncthreads(); }
  if (i==0) atomicMax((unsigned int*)(scal+2), __float_as_uint(red[0]));
}

// ---------------- e = exp(s1*(height-hmax)), prefix sums ----------------
__global__ __launch_bounds__(128) void ep_k(const float* height, const float* scal, float* e, float* P){
  int b = blockIdx.x, l = threadIdx.x;
  __shared__ float red[128], sc[128];
  float h = height[b*128+l];
  red[l] = h; __syncthreads();
  for (int s=64;s>0;s>>=1){ if (l<s) red[l] = fmaxf(red[l], red[l+s]); __syncthreads(); }
  float hmax = red[0];
  float ev = expf(scal[1]*(h - hmax));
  e[b*128+l] = ev;
  sc[l] = ev; __syncthreads();
  for (int off=1; off<128; off<<=1){
    float a = (l>=off) ? sc[l-off] : 0.f;
    __syncthreads(); sc[l] += a; __syncthreads();
  }
  P[b*132 + l + 1] = sc[l];
  if (l==0) P[b*132] = 0.f;
}

// ---------------- gamma -> bml/bmr via sequential cummin scans ----------------
__global__ __launch_bounds__(128) void gbml_k(const float* height, const float* dist, const float* scal,
                                              float* bml, float* bmr){
  int b = blockIdx.x, l = threadIdx.x;
  __shared__ float dAdj[128], hg[128];
  float dmax = scal[2], s0 = scal[0];
  dAdj[l] = dist[b*128+l] - dmax; hg[l] = height[b*128+l];
  __syncthreads();
  float hl = hg[l];
  float* BML = bml + ((size_t)b*128 + l)*128;
  float* BMR = bmr + ((size_t)b*128 + l)*128;
  for (int j=l+1; j<128; ++j) BML[j] = 0.f;
  float cmn = 1.f;
  for (int j=l-1; j>=0; --j){
    float g = 1.f/(1.f + expf(-(hl - dAdj[j])*s0));
    float cmj = fminf(g, cmn);
    BML[j+1] = cmn - cmj;
    cmn = cmj;
  }
  BML[0] = cmn;
  for (int j=0; j<l; ++j) BMR[j] = 0.f;
  float cmp_ = 1.f;
  for (int j=l+1; j<128; ++j){
    float g = 1.f/(1.f + expf(-(hl - dAdj[j-1])*s0));
    float cmj = fminf(g, cmp_);
    BMR[j-1] = cmp_ - cmj;
    cmp_ = cmj;
  }
  BMR[127] = cmp_;
}

// ---------------- head via separable prefix/suffix sums ----------------
__global__ __launch_bounds__(128) void head_k(const float* bml, const float* bmr, const float* e,
                                              const float* P, float* head){
  int bl = blockIdx.x; int b = bl>>7, l = bl&127; int h = threadIdx.x;
  __shared__ float bmlS[128], bmrS[128], eS[128], PS[129], U[128], Vv[128];
  bmlS[h] = bml[(size_t)bl*128 + h];
  bmrS[h] = bmr[(size_t)bl*128 + h];
  eS[h]   = e[b*128+h];
  PS[h]   = P[b*132+h];
  if (h==0) PS[128] = P[b*132+128];
  __syncthreads();
  float u = 0.f, v = 0.f;
  if (h <= l){
    float bh = bmlS[h];
    if (bh > 0.f){
      float ph = PS[h]; float acc = 0.f;
      for (int j=l; j<128; ++j){
        float br = bmrS[j]; float den = PS[j+1] - ph;
        if (br > 0.f && den > 1e-30f) acc += br/den;
      }
      u = bh*acc;
    }
  } else {
    float br = bmrS[h];
    if (br > 0.f){
      float p1 = PS[h+1]; float acc = 0.f;
      for (int i=0;i<=l;++i){
        float bm = bmlS[i]; float den = p1 - PS[i];
        if (bm > 0.f && den > 1e-30f) acc += bm/den;
      }
      v = br*acc;
    }
  }
  U[h] = u; Vv[h] = v; __syncthreads();
  for (int off=1; off<128; off<<=1){
    float a  = (h>=off)      ? U[h-off]  : 0.f;
    float bs = (h+off<128)   ? Vv[h+off] : 0.f;
    __syncthreads();
    U[h] += a; Vv[h] += bs;
    __syncthreads();
  }
  float a = (h<l) ? U[h] : (h>l) ? Vv[h] : 0.f;   // eye zeroed at h==l
  head[(size_t)bl*128 + h] = eS[h]*a;
}

// ---------------- v -> vT per (b,head) ----------------
__global__ __launch_bounds__(256) void vtrans_k(const bf16* qkv, bf16* vt){
  __shared__ short tl[64*130];
  const short* q = (const short*)qkv; short* v = (short*)vt;
  int z = blockIdx.x, t = threadIdx.x; int b = z>>3, h = z&7;
  for (int i=t; i<8192; i+=256){ int l = i>>6, d = i&63;
    tl[d*130 + l] = q[((size_t)(b*128+l))*1536 + 1024 + h*64 + d]; }
  __syncthreads();
  for (int i=t; i<8192; i+=256){ v[(size_t)z*8192 + i] = tl[(i>>7)*130 + (i&127)]; }
}

// ---------------- MFMA NT GEMM: C[M,N] = A[M,K] @ Bt[N,K]^T (+epilogues) ----------------
// SPLIT=1: blockIdx.z = K-split index; partials accumulated with fp32 atomicAdd.
// LDS: 64x64 tiles, XOR-swizzled 8-element groups (global_load_lds-compatible, ds_read 2-way free).
enum GMode { GM_F32=0, GM_BF16=1, GM_LEAKY=2, GM_ADD=3, GM_SIGDEP=4 };

template<int MODE, int SPLIT>
__global__ __launch_bounds__(256) void gemm_nt(
    const bf16* __restrict__ Ab, int lda, long long sA1, long long sA2,
    const bf16* __restrict__ Bb, int ldb, long long sB1, long long sB2,
    void* __restrict__ Cb, int ldc, long long sC1, long long sC2,
    int M, int N, int K, int kchunk,
    const float* __restrict__ bias,
    const int* __restrict__ maskp, const float* __restrict__ headp,
    const float* __restrict__ scal, int layer)
{
  __shared__ short As[2][4096];
  __shared__ short Bs[2][4096];
  const int t = threadIdx.x;
  int zb = 0, zh = 0, kbeg = 0, kend = K;
  if (SPLIT){ kbeg = blockIdx.z*kchunk; kend = min(K, kbeg + kchunk); }
  else { int z = blockIdx.z; zb = z>>3; zh = z&7; }
  const bf16* A  = Ab + (size_t)zb*sA1 + (size_t)zh*sA2 + (size_t)blockIdx.y*64*lda;
  const bf16* Bp = Bb + (size_t)zb*sB1 + (size_t)zh*sB2;
  const int n0 = blockIdx.x*64;
  const int wv = t>>6, ln = t&63;
  const int wm = wv>>1, wn = wv&1;          // 2x2 wave layout, each wave 32x32

  f32x4 acc[2][2];
  #pragma unroll
  for (int mi=0;mi<2;++mi)
    #pragma unroll
    for (int ci=0;ci<2;++ci) acc[mi][ci] = (f32x4){0.f,0.f,0.f,0.f};

  // staging: wave wv covers rows [wv*16, wv*16+16) of both A and B tiles,
  // 2 global_load_lds_dwordx4 instrs each (8 rows x 64 shorts per instr).
  auto stage = [&](int buf, int k0){
    #pragma unroll
    for (int q=0;q<2;++q){
      int r0 = wv*16 + q*8;
      int row = r0 + (ln>>3);
      int gs = (ln&7) ^ (row&7);          // XOR swizzle on 8-short groups
      gll16(A + (size_t)row*lda + k0 + gs*8, &As[buf][r0*64]);
      int rb = n0 + row; if (rb >= N) rb = N-1;   // clamp (garbage cols masked at write)
      gll16(Bp + (size_t)rb*ldb + k0 + gs*8, &Bs[buf][r0*64]);
    }
  };

  const int nIter = (kend - kbeg) >> 6;
  stage(0, kbeg);
  for (int it=0; it<nIter; ++it){
    const int cur = it & 1;
    __syncthreads();                       // drains staging of buf[cur] (and prior reads)
    if (it+1 < nIter) stage(cur^1, kbeg + (it+1)*64);   // prefetch flies during MFMA below
    #pragma unroll
    for (int kk=0; kk<64; kk+=32){
      short8 av[2], bv[2];
      #pragma unroll
      for (int mi=0;mi<2;++mi){
        int r = wm*32 + mi*16 + (ln&15);
        int gg = (kk>>3) + (ln>>4);
        av[mi] = *(const short8*)(&As[cur][r*64 + ((gg ^ (r&7))<<3)]);
      }
      #pragma unroll
      for (int ci=0;ci<2;++ci){
        int r = wn*32 + ci*16 + (ln&15);
        int gg = (kk>>3) + (ln>>4);
        bv[ci] = *(const short8*)(&Bs[cur][r*64 + ((gg ^ (r&7))<<3)]);
      }
      #pragma unroll
      for (int mi=0;mi<2;++mi)
        #pragma unroll
        for (int ci=0;ci<2;++ci)
          acc[mi][ci] = __builtin_amdgcn_mfma_f32_16x16x32_bf16(av[mi], bv[ci], acc[mi][ci], 0,0,0);
    }
  }

  const int cin = ln & 15;
  #pragma unroll
  for (int mi=0;mi<2;++mi){
    #pragma unroll
    for (int ci=0;ci<2;++ci){
      int col = n0 + wn*32 + ci*16 + cin;
      if (col >= N) continue;
      #pragma unroll
      for (int r=0;r<4;++r){
        int row = blockIdx.y*64 + wm*32 + mi*16 + ((ln>>4)<<2) + r;
        float v = acc[mi][ci][r];
        size_t coff = (size_t)zb*sC1 + (size_t)zh*sC2 + (size_t)row*ldc + col;
        if (MODE == GM_F32){
          if (SPLIT) atomicAdd(((float*)Cb) + coff, v);   // bias folded into consumer
          else { if (bias) v += bias[col]; ((float*)Cb)[coff] = v; }
        } else if (MODE == GM_BF16){
          if (bias) v += bias[col];
          ((bf16*)Cb)[coff] = f2b(v);
        } else if (MODE == GM_LEAKY){
          v += bias[col];
          v = (v > 0.f) ? v : 0.01f*v;
          ((bf16*)Cb)[coff] = f2b(v);
        } else if (MODE == GM_ADD){
          float add = (!SPLIT || blockIdx.z == 0) ? bias[col] : 0.f;
          atomicAdd(((float*)Cb) + coff, v + add);
        } else { // GM_SIGDEP: w = sigmoid(qk/8 + kpm) * (rw0*head[l,m] + rw1*head[m,l])
          float outv = 0.f;
          if (maskp[zb*128 + col] != 0){
            float sg = 1.f/(1.f + expf(-v*0.125f));
            float h1 = headp[((size_t)zb*128 + row)*128 + col];
            float h2 = headp[((size_t)zb*128 + col)*128 + row];
            float rw0 = scal[4 + (layer*8 + zh)*2];
            float rw1 = scal[4 + (layer*8 + zh)*2 + 1];
            outv = sg*(rw0*h1 + rw1*h2);
          }
          ((bf16*)Cb)[coff] = f2b(outv);
        }
      }
    }
  }
}

// ---------------- launch ----------------
extern "C" void kernel_launch(void* const* d_in, const int* in_sizes, int n_in,
                              void* d_out, int out_size, void* d_ws, size_t ws_size,
                              hipStream_t stream)
{
  if (ws_size < WS_NEED) return;  // need ~97 MB of scratch
  const int*   x    = (const int*)d_in[0];
  const float* emb  = (const float*)d_in[2];
  const float* pw   = (const float*)d_in[3];
  const float* pcb  = (const float*)d_in[4];
  const float* dw   = (const float*)d_in[5];
  const float* dcb  = (const float*)d_in[6];
  const float* dlw  = (const float*)d_in[7];
  const float* dlb  = (const float*)d_in[8];
  const float* hw1  = (const float*)d_in[9];
  const float* hb1  = (const float*)d_in[10];
  const float* hw2  = (const float*)d_in[11];
  const float* hb2  = (const float*)d_in[12];
  const float* relw = (const float*)d_in[13];
  const float* sraw = (const float*)d_in[14];
  const float* alg  = (const float*)d_in[15];
  const float* alb  = (const float*)d_in[16];
  const float* qw   = (const float*)d_in[17];
  const float* qb   = (const float*)d_in[18];
  const float* kw   = (const float*)d_in[19];
  const float* kb   = (const float*)d_in[20];
  const float* vw   = (const float*)d_in[21];
  const float* vb   = (const float*)d_in[22];
  const float* ow   = (const float*)d_in[23];
  const float* ob   = (const float*)d_in[24];
  const float* flg  = (const float*)d_in[25];
  const float* flb  = (const float*)d_in[26];
  const float* f1   = (const float*)d_in[27];
  const float* fb1  = (const float*)d_in[28];
  const float* f2   = (const float*)d_in[29];
  const float* fb2  = (const float*)d_in[30];
  const float* fng  = (const float*)d_in[31];
  const float* fnb  = (const float*)d_in[32];
  const float* outb = (const float*)d_in[33];

  char* ws = (char*)d_ws;
  float* scal    = (float*)(ws + SCAL_OFF);
  float* biasf   = (float*)(ws + BIASF_OFF);
  int*   maskp   = (int*)(ws + MASK_OFF);
  float* heightp = (float*)(ws + HEIGHT_OFF);
  float* distp   = (float*)(ws + DIST_OFF);
  float* e_p     = (float*)(ws + E_OFF);
  float* P_p     = (float*)(ws + P_OFF);
  float* h0      = (float*)(ws + H0_OFF);
  float* tmpf    = (float*)(ws + TMPF_OFF);
  bf16* hm_bf    = (bf16*)(ws + HMBF_OFF);
  bf16* h_bf     = (bf16*)(ws + HBF_OFF);
  bf16* z_bf     = (bf16*)(ws + ZBF_OFF);
  bf16* qkvp     = (bf16*)(ws + QKV_OFF);
  bf16* vtp      = (bf16*)(ws + VT_OFF);
  bf16* wattp    = (bf16*)(ws + WATT_OFF);
  bf16* o_bf     = (bf16*)(ws + OBF_OFF);
  bf16* ff1p     = (bf16*)(ws + FF1_OFF);
  bf16* acol     = (bf16*)(ws + ACOL_OFF);
  float* bmlp    = (float*)(ws + BML_OFF);
  float* bmrp    = (float*)(ws + BMR_OFF);
  float* headp   = (float*)(ws + HEADP_OFF);
  bf16* pwT      = (bf16*)(ws + PWT_OFF);
  bf16* dwT      = (bf16*)(ws + DWT_OFF);
  bf16* hw1T     = (bf16*)(ws + HW1T_OFF);
  bf16* qkvT     = (bf16*)(ws + QKVT_OFF);
  bf16* owT      = (bf16*)(ws + OWT_OFF);
  bf16* f1T      = (bf16*)(ws + F1T_OFF);
  bf16* f2T      = (bf16*)(ws + F2T_OFF);
  bf16* embB     = (bf16*)(ws + QKV_OFF);   // reuse attention scratch after the loop

  prep_k<<<196,256,0,stream>>>(pcb,dcb,hb1,qb,kb,vb,ob,fb1,fb2,outb,relw,sraw,biasf,scal);
  TP tp{pw,dw,hw1,qw,kw,vw,ow,f1,f2, pwT,dwT,hw1T,qkvT,owT,f1T,f2T};
  transpose_all_k<<<34560,256,0,stream>>>(tp);
  embed_k<<<1024,256,0,stream>>>(x, emb, h0, hm_bf, maskp);

  const size_t TMPB = (size_t)1024*512*4;
  // parser: 4x (conv K=9 -> split-K GEMM -> LN -> tanh)
  for (int i=0;i<4;++i){
    im2col9_k<<<dim3(1024,9),64,0,stream>>>(hm_bf, acol);
    hipMemsetAsync(tmpf, 0, TMPB, stream);
    gemm_nt<GM_F32,1><<<dim3(8,16,6),256,0,stream>>>(acol,4608,0,0, pwT+(size_t)i*2359296,4608,0,0,
        tmpf,512,0,0, 1024,512,4608,768, nullptr, nullptr,nullptr,nullptr,0);
    ln_tanh_k<<<1024,256,0,stream>>>(tmpf, biasf + i*512, hm_bf, h_bf, maskp);
  }
  // height head
  hipMemsetAsync(tmpf, 0, TMPB, stream);
  gemm_nt<GM_F32,1><<<dim3(8,16,2),256,0,stream>>>(h_bf,512,0,0, hw1T,512,0,0,
      tmpf,512,0,0, 1024,512,512,256, nullptr, nullptr,nullptr,nullptr,0);
  ln_tanh_k<<<1024,256,0,stream>>>(tmpf, biasf + 2560, hm_bf, z_bf, maskp);
  rowdot_k<<<256,256,0,stream>>>(z_bf, hw2, hb2, maskp, heightp, 0);
  ep_k<<<8,128,0,stream>>>(heightp, scal, e_p, P_p);
  // distance head (conv K=2, shift)
  im2col2_k<<<dim3(1024,2),64,0,stream>>>(h_bf, acol);
  hipMemsetAsync(tmpf, 0, TMPB, stream);
  gemm_nt<GM_F32,1><<<dim3(8,16,2),256,0,stream>>>(acol,1024,0,0, dwT,1024,0,0,
      tmpf,512,0,0, 1024,512,1024,512, nullptr, nullptr,nullptr,nullptr,0);
  ln_tanh_k<<<1024,256,0,stream>>>(tmpf, biasf + 2048, hm_bf, z_bf, maskp);
  rowdot_k<<<256,256,0,stream>>>(z_bf, dlw, dlb, maskp, distp, 1);
  // margin normalization, block decomposition, head distribution
  margin_k<<<8,128,0,stream>>>(heightp, distp, maskp, scal);
  gbml_k<<<8,128,0,stream>>>(heightp, distp, scal, bmlp, bmrp);
  head_k<<<1024,128,0,stream>>>(bmlp, bmrp, e_p, P_p, headp);

  // transformer
  for (int l=0;l<8;++l){
    ln_affine_k<<<1024,256,0,stream>>>(h0, alg + l*512, alb + l*512, z_bf);
    gemm_nt<GM_BF16,0><<<dim3(24,16,1),256,0,stream>>>(z_bf,512,0,0, qkvT+(size_t)l*786432,512,0,0,
        qkvp,1536,0,0, 1024,1536,512,0, biasf + 3072 + l*1536, nullptr,nullptr,nullptr,0);
    vtrans_k<<<64,256,0,stream>>>(qkvp, vtp);
    gemm_nt<GM_SIGDEP,0><<<dim3(2,2,64),256,0,stream>>>(qkvp,1536,196608,64, qkvp+512,1536,196608,64,
        wattp,128,131072,16384, 128,128,64,0, nullptr, maskp, headp, scal, l);
    gemm_nt<GM_BF16,0><<<dim3(1,2,64),256,0,stream>>>(wattp,128,131072,16384, vtp,128,65536,8192,
        o_bf,512,65536,64, 128,64,128,0, nullptr, nullptr,nullptr,nullptr,0);
    gemm_nt<GM_ADD,1><<<dim3(8,16,2),256,0,stream>>>(o_bf,512,0,0, owT+(size_t)l*262144,512,0,0,
        h0,512,0,0, 1024,512,512,256, biasf + 15360 + l*512, nullptr,nullptr,nullptr,0);
    ln_affine_k<<<1024,256,0,stream>>>(h0, flg + l*512, flb + l*512, z_bf);
    gemm_nt<GM_LEAKY,0><<<dim3(32,16,1),256,0,stream>>>(z_bf,512,0,0, f1T+(size_t)l*1048576,512,0,0,
        ff1p,2048,0,0, 1024,2048,512,0, biasf + 19456 + l*2048, nullptr,nullptr,nullptr,0);
    gemm_nt<GM_ADD,1><<<dim3(8,16,4),256,0,stream>>>(ff1p,2048,0,0, f2T+(size_t)l*1048576,2048,0,0,
        h0,512,0,0, 1024,512,2048,512, biasf + 35840 + l*512, nullptr,nullptr,nullptr,0);
  }
  // final LN + tied-embedding projection (fp32 out)
  ln_affine_k<<<1024,256,0,stream>>>(h0, fng, fnb, z_bf);
  embcast_k<<<5000,256,0,stream>>>(emb, embB);
  gemm_nt<GM_F32,0><<<dim3(157,16,1),256,0,stream>>>(z_bf,512,0,0, embB,512,0,0,
      d_out,10000,0,0, 1024,10000,512,0, biasf + 39936, nullptr,nullptr,nullptr,0);
}